// Round 1
// 538.205 us; speedup vs baseline: 1.0378x; 1.0378x over previous
//
#include <hip/hip_runtime.h>

#define F_IN 512
#define F_HID 16
#define F_OUT 7
#define BUCKET 128          // nodes per bucket
#define LB 7                // log2(BUCKET)
#define TRASH 128           // dl value for sentinel pad edges in bedges
#define PADV 128            // packed sentinel: src=0, dl=TRASH
#define CHUNK 8192          // edges per partition block
#define MAXNB 1024          // max buckets supported by scans

// GEMM1 tiling
#define RPB 256             // rows per block
#define KC 32               // staged k-chunk
#define KHALF 256           // K range per split block (F_IN / KSPLIT)
#define LSTRIDE 33          // LDS row stride (pad: 2-way bank aliasing = free)

typedef int   int4v   __attribute__((ext_vector_type(4)));
typedef float float4v __attribute__((ext_vector_type(4)));
typedef unsigned int uint4v __attribute__((ext_vector_type(4)));

static __device__ __forceinline__ unsigned short f2bf(float f) {   // RNE
    unsigned int u = __float_as_uint(f);
    u += 0x7FFFu + ((u >> 16) & 1u);
    return (unsigned short)(u >> 16);
}
static __device__ __forceinline__ float bf2f(unsigned short s) {
    return __uint_as_float((unsigned int)s << 16);
}

// ---------------- zero int array ----------------
__global__ void k_zero(int* __restrict__ p, int n) {
    int i = blockIdx.x * blockDim.x + threadIdx.x;
    if (i < n) p[i] = 0;
}

// ---------------- bucket histogram ----------------
__global__ void k_bhist(const int* __restrict__ dst, int* __restrict__ bucket_cnt, int E, int NB) {
    __shared__ int hist[MAXNB];
    int t = threadIdx.x;
    for (int i = t; i < NB; i += 256) hist[i] = 0;
    __syncthreads();
    int base = blockIdx.x * CHUNK;
#pragma unroll
    for (int i = 0; i < CHUNK / 256; ++i) {
        int e = base + i * 256 + t;
        if (e < E) atomicAdd(&hist[__builtin_nontemporal_load(dst + e) >> LB], 1);
    }
    __syncthreads();
    for (int i = t; i < NB; i += 256)
        if (hist[i]) atomicAdd(&bucket_cnt[i], hist[i]);
}

// ---- scan 1: exclusive scan of 4-aligned bucket counts + sentinel pad tails ----
__global__ void k_bscan1(const int* __restrict__ bucket_cnt, int* __restrict__ bucket_base,
                         int* __restrict__ cursor, int* __restrict__ bedges, int NB) {
    __shared__ int sm[MAXNB];
    int t = threadIdx.x;                       // 1024 threads
    int c = (t < NB) ? bucket_cnt[t] : 0;
    int ca = (c + 3) & ~3;
    sm[t] = ca;
    __syncthreads();
    for (int off = 1; off < MAXNB; off <<= 1) {
        int v = sm[t];
        int add = (t >= off) ? sm[t - off] : 0;
        __syncthreads();
        sm[t] = v + add;
        __syncthreads();
    }
    if (t < NB) {
        int base = sm[t] - ca;
        bucket_base[t] = base;
        cursor[t] = base;
        for (int i = c; i < ca; ++i) bedges[base + i] = PADV;
    }
}

// ---------------- partition: packed edges into bucket segments ----------------
__global__ void k_place(const int* __restrict__ src, const int* __restrict__ dst,
                        int* __restrict__ cursor, int* __restrict__ bedges, int E, int NB) {
    __shared__ int hist[MAXNB];
    __shared__ int lcur[MAXNB];
    int t = threadIdx.x;
    for (int i = t; i < NB; i += 256) hist[i] = 0;
    __syncthreads();
    int base = blockIdx.x * CHUNK;
#pragma unroll
    for (int i = 0; i < CHUNK / 256; ++i) {
        int e = base + i * 256 + t;
        if (e < E) atomicAdd(&hist[__builtin_nontemporal_load(dst + e) >> LB], 1);
    }
    __syncthreads();
    for (int i = t; i < NB; i += 256)
        lcur[i] = hist[i] ? atomicAdd(&cursor[i], hist[i]) : 0;
    __syncthreads();
#pragma unroll
    for (int i = 0; i < CHUNK / 256; ++i) {
        int e = base + i * 256 + t;
        if (e < E) {
            int d = __builtin_nontemporal_load(dst + e);
            int s = __builtin_nontemporal_load(src + e);
            int b = d >> LB;
            int pos = atomicAdd(&lcur[b], 1);
            __builtin_nontemporal_store((s << 8) | (d & (BUCKET - 1)), bedges + pos);
        }
    }
}

// ---- per-bucket: degree hist -> dinv, within-bucket 4-padded offsets, bucket padded size ----
__global__ void k_pcount(const int* __restrict__ bucket_base, const int* __restrict__ bucket_cnt,
                         const int* __restrict__ bedges, float* __restrict__ dinv,
                         int* __restrict__ node_off, int* __restrict__ bucket_psize, int n) {
    __shared__ int cnt[TRASH + 8];             // bins 0..128 (128 = sentinel trash)
    __shared__ int sc[BUCKET];
    int b = blockIdx.x, t = threadIdx.x;       // 256 threads
    for (int i = t; i < TRASH + 8; i += 256) cnt[i] = 0;
    __syncthreads();
    int base = bucket_base[b], ne = bucket_cnt[b];
    int nqq = (ne + 3) >> 2;
    for (int qi = t; qi < nqq; qi += 256) {
        int4v q = __builtin_nontemporal_load((const int4v*)(bedges + base + (qi << 2)));
        atomicAdd(&cnt[q.x & 255], 1);
        atomicAdd(&cnt[q.y & 255], 1);
        atomicAdd(&cnt[q.z & 255], 1);
        atomicAdd(&cnt[q.w & 255], 1);
    }
    __syncthreads();
    int p = 0;
    if (t < BUCKET) { p = (cnt[t] + 3) & ~3; sc[t] = p; }
    __syncthreads();
    for (int off = 1; off < BUCKET; off <<= 1) {
        int v = 0;
        if (t < BUCKET) { v = sc[t]; if (t >= off) v += sc[t - off]; }
        __syncthreads();
        if (t < BUCKET) sc[t] = v;
        __syncthreads();
    }
    if (t < BUCKET) {
        int node = b * BUCKET + t;
        if (node < n) {
            dinv[node] = rsqrtf((float)(cnt[t] + 1));   // +1 self-loop
            node_off[node] = sc[t] - p;                 // within-bucket padded offset (woff)
        }
        if (t == BUCKET - 1) bucket_psize[b] = sc[t];
    }
}

// ---- scan 2: exclusive scan of padded bucket sizes -> pbase ----
__global__ void k_bscan2(const int* __restrict__ bucket_psize, int* __restrict__ pbase, int NB) {
    __shared__ int sm[MAXNB];
    int t = threadIdx.x;                       // 1024 threads
    int c = (t < NB) ? bucket_psize[t] : 0;
    sm[t] = c;
    __syncthreads();
    for (int off = 1; off < MAXNB; off <<= 1) {
        int v = sm[t];
        int add = (t >= off) ? sm[t - off] : 0;
        __syncthreads();
        sm[t] = v + add;
        __syncthreads();
    }
    if (t < NB) pbase[t] = sm[t] - c;
}

// ---- per-bucket counting sort by dl: bedges -> bedges2 (src only, per-node 4-padded runs) ----
__global__ void k_sort(const int* __restrict__ bucket_base, const int* __restrict__ bucket_cnt,
                       const int* __restrict__ pbase, const int* __restrict__ bedges,
                       int* __restrict__ bedges2, int* __restrict__ node_off,
                       int* __restrict__ node_nq, int n) {
    __shared__ int cur[BUCKET];
    __shared__ int woffs[BUCKET];
    int b = blockIdx.x, t = threadIdx.x;       // 256 threads
    int pb = pbase[b];
    if (t < BUCKET) {
        int node = b * BUCKET + t;
        int w = (node < n) ? node_off[node] : 0;
        woffs[t] = w;
        cur[t] = w;
    }
    __syncthreads();
    int base = bucket_base[b], ne = bucket_cnt[b];
    int nqq = (ne + 3) >> 2;
    for (int qi = t; qi < nqq; qi += 256) {
        int4v q = __builtin_nontemporal_load((const int4v*)(bedges + base + (qi << 2)));
        int v, dl, pos;
        v = q.x; dl = v & 255;
        if (dl < BUCKET) { pos = atomicAdd(&cur[dl], 1); bedges2[pb + pos] = v >> 8; }
        v = q.y; dl = v & 255;
        if (dl < BUCKET) { pos = atomicAdd(&cur[dl], 1); bedges2[pb + pos] = v >> 8; }
        v = q.z; dl = v & 255;
        if (dl < BUCKET) { pos = atomicAdd(&cur[dl], 1); bedges2[pb + pos] = v >> 8; }
        v = q.w; dl = v & 255;
        if (dl < BUCKET) { pos = atomicAdd(&cur[dl], 1); bedges2[pb + pos] = v >> 8; }
    }
    __syncthreads();
    if (t < BUCKET) {
        int node = b * BUCKET + t;
        if (node < n) {
            int w = woffs[t];
            int endc = cur[t];
            int cnt = endc - w;
            int p = (cnt + 3) & ~3;
            for (int i = endc; i < w + p; ++i) bedges2[pb + i] = n;   // sentinel -> zero row
            node_off[node] = pb + w;                                  // now GLOBAL offset
            node_nq[node] = p >> 2;
        }
    }
}

// -------- GEMM1 (rewritten): K-split x2, LDS-coalesced x staging, fp32 partials --------
// block = 256 threads = 256 rows, K-half of 256. Thread-per-row compute keeps W
// wave-uniform (s_load streamed). x staged [256][32] per chunk via full-128B-line
// coalesced loads; LSTRIDE=33 pad -> 2-way bank aliasing (free).
__global__ __launch_bounds__(256) void k_gemm1p(
        const float* __restrict__ x, const float* __restrict__ W,
        float* __restrict__ part, int n) {
    __shared__ float xs[RPB * LSTRIDE];        // 33792 B
    int b  = blockIdx.x >> 1;
    int ks = blockIdx.x & 1;
    int r0 = b * RPB;
    int t  = threadIdx.x;
    int r  = r0 + t;
    int kbase = ks * KHALF;

    float acc[F_HID];
#pragma unroll
    for (int c = 0; c < F_HID; ++c) acc[c] = 0.0f;

    int lr0 = t >> 3;                           // 0..31 (stage row group)
    int c4  = t & 7;                            // 0..7  (float4 slot: 8 x 16B = 128B/row)

    for (int kc = 0; kc < KHALF; kc += KC) {
        __syncthreads();                        // xs reads of previous chunk done
#pragma unroll
        for (int j = 0; j < 8; ++j) {
            int lr = j * 32 + lr0;
            int gr = r0 + lr;
            float4v v = {0.0f, 0.0f, 0.0f, 0.0f};
            if (gr < n)
                v = *(const float4v*)(x + (size_t)gr * F_IN + kbase + kc + c4 * 4);
            float* d = xs + lr * LSTRIDE + c4 * 4;
            d[0] = v.x; d[1] = v.y; d[2] = v.z; d[3] = v.w;
        }
        __syncthreads();
        if (r < n) {
            const float* xrow = xs + t * LSTRIDE;
            const float* Wk = W + (size_t)(kbase + kc) * F_HID;
#pragma unroll
            for (int k = 0; k < KC; ++k) {
                float xv = xrow[k];
#pragma unroll
                for (int c = 0; c < F_HID; ++c)
                    acc[c] = fmaf(xv, Wk[k * F_HID + c], acc[c]);
            }
        }
    }
    if (r < n) {
        float4v* o = (float4v*)(part + ((size_t)ks * n + r) * F_HID);
        float4v w0 = {acc[0],  acc[1],  acc[2],  acc[3]};
        float4v w1 = {acc[4],  acc[5],  acc[6],  acc[7]};
        float4v w2 = {acc[8],  acc[9],  acc[10], acc[11]};
        float4v w3 = {acc[12], acc[13], acc[14], acc[15]};
        o[0] = w0; o[1] = w1; o[2] = w2; o[3] = w3;
    }
}

// -------- finalize GEMM1: sum K-split partials, scale by dinv, -> bf16 h1b --------
// 16 lanes per row; coalesced 64B-per-4-rows loads; row n = sentinel zeros.
__global__ void k_fin1(const float* __restrict__ part, const float* __restrict__ dinv,
                       unsigned short* __restrict__ h1b, int n) {
    int tg = blockIdx.x * 256 + threadIdx.x;
    int r = tg >> 4, c = tg & 15;
    if (r > n) return;
    if (r == n) { h1b[(size_t)r * F_HID + c] = 0; return; }
    float v = part[(size_t)r * F_HID + c] + part[((size_t)n + r) * F_HID + c];
    h1b[(size_t)r * F_HID + c] = f2bf(dinv[r] * v);
}

// ------ agg layer 1: 16 lanes/node, CSR quads, REGISTER accumulation, no atomics ------
__global__ __launch_bounds__(1024) void k_agg1(
        const int* __restrict__ node_off, const int* __restrict__ node_nq,
        const int* __restrict__ bedges2, const unsigned short* __restrict__ h1b,
        const float* __restrict__ dinv, float* __restrict__ agg1, int n) {
    int tg = blockIdx.x * 1024 + threadIdx.x;
    int node = tg >> 4, c = tg & 15;
    if (node >= n) return;
    int off = node_off[node], nq = node_nq[node];
    float acc = bf2f(h1b[(size_t)node * F_HID + c]);    // self-loop (pre-scaled)
    for (int q = 0; q < nq; ++q) {
        int4v s = *(const int4v*)(bedges2 + off + (q << 2));
        float v0 = bf2f(h1b[(size_t)s.x * F_HID + c]);
        float v1 = bf2f(h1b[(size_t)s.y * F_HID + c]);
        float v2 = bf2f(h1b[(size_t)s.z * F_HID + c]);
        float v3 = bf2f(h1b[(size_t)s.w * F_HID + c]);
        acc += v0 + v1 + v2 + v3;
    }
    agg1[(size_t)node * F_HID + c] = dinv[node] * acc;
}

// ---- relu+bias1+GEMM2, h2b = bf16(dinv * h2) (stride 8, col7 = 0); row n zeros ----
__global__ void k_layer2(const float* __restrict__ agg1, const float* __restrict__ b1,
                         const float* __restrict__ W2, const float* __restrict__ dinv,
                         unsigned short* __restrict__ h2b, int n) {
    int r = blockIdx.x * blockDim.x + threadIdx.x;
    if (r > n) return;
    if (r == n) {
        uint4v z = {0u, 0u, 0u, 0u};
        *(uint4v*)(h2b + (size_t)r * 8) = z;
        return;
    }
    float z[F_HID];
    const float4* ai = (const float4*)(agg1 + (size_t)r * F_HID);
#pragma unroll
    for (int q = 0; q < 4; ++q) {
        float4 v = ai[q];
        z[q * 4 + 0] = fmaxf(v.x + b1[q * 4 + 0], 0.0f);
        z[q * 4 + 1] = fmaxf(v.y + b1[q * 4 + 1], 0.0f);
        z[q * 4 + 2] = fmaxf(v.z + b1[q * 4 + 2], 0.0f);
        z[q * 4 + 3] = fmaxf(v.w + b1[q * 4 + 3], 0.0f);
    }
    float h[F_OUT];
#pragma unroll
    for (int c = 0; c < F_OUT; ++c) h[c] = 0.0f;
#pragma unroll
    for (int k = 0; k < F_HID; ++k)
#pragma unroll
        for (int c = 0; c < F_OUT; ++c)
            h[c] = fmaf(z[k], W2[k * F_OUT + c], h[c]);
    float dv = dinv[r];
    uint4v w;
    w.x = (unsigned)f2bf(dv * h[0]) | ((unsigned)f2bf(dv * h[1]) << 16);
    w.y = (unsigned)f2bf(dv * h[2]) | ((unsigned)f2bf(dv * h[3]) << 16);
    w.z = (unsigned)f2bf(dv * h[4]) | ((unsigned)f2bf(dv * h[5]) << 16);
    w.w = (unsigned)f2bf(dv * h[6]);
    *(uint4v*)(h2b + (size_t)r * 8) = w;
}

// ------ agg layer 2: 8 lanes/node, CSR quads, register accumulation, writes out ------
__global__ __launch_bounds__(1024) void k_agg2(
        const int* __restrict__ node_off, const int* __restrict__ node_nq,
        const int* __restrict__ bedges2, const unsigned short* __restrict__ h2b,
        const float* __restrict__ dinv, const float* __restrict__ b2,
        float* __restrict__ out, int n) {
    int tg = blockIdx.x * 1024 + threadIdx.x;
    int node = tg >> 3, c = tg & 7;
    if (node >= n) return;
    int off = node_off[node], nq = node_nq[node];
    float acc = bf2f(h2b[(size_t)node * 8 + c]);        // self-loop (col7 = 0)
    for (int q = 0; q < nq; ++q) {
        int4v s = *(const int4v*)(bedges2 + off + (q << 2));
        float v0 = bf2f(h2b[(size_t)s.x * 8 + c]);
        float v1 = bf2f(h2b[(size_t)s.y * 8 + c]);
        float v2 = bf2f(h2b[(size_t)s.z * 8 + c]);
        float v3 = bf2f(h2b[(size_t)s.w * 8 + c]);
        acc += v0 + v1 + v2 + v3;
    }
    if (c < F_OUT)
        out[(size_t)node * F_OUT + c] = dinv[node] * acc + b2[c];
}

extern "C" void kernel_launch(void* const* d_in, const int* in_sizes, int n_in,
                              void* d_out, int out_size, void* d_ws, size_t ws_size,
                              hipStream_t stream) {
    const float* x  = (const float*)d_in[0];
    const int*   ei = (const int*)d_in[1];      // int64 in source but JAX x64 off -> int32
    const float* W1 = (const float*)d_in[2];
    const float* b1 = (const float*)d_in[3];
    const float* W2 = (const float*)d_in[4];
    const float* b2 = (const float*)d_in[5];
    float* out = (float*)d_out;

    const int n = in_sizes[0] / F_IN;       // 100000
    const int E = in_sizes[1] / 2;          // 3200000
    const int* src = ei;
    const int* dst = ei + E;

    const int NB = (n + BUCKET - 1) / BUCKET;   // 782 (<= MAXNB)
    const int PBLK = (E + CHUNK - 1) / CHUNK;

    // workspace layout (16B-aligned sections)
    size_t Np = ((size_t)n + 3) & ~(size_t)3;
    char* ws = (char*)d_ws;
    int*   bucket_cnt   = (int*)ws;             ws += MAXNB * 4;
    int*   bucket_base  = (int*)ws;             ws += MAXNB * 4;
    int*   cursor       = (int*)ws;             ws += MAXNB * 4;
    int*   bucket_psize = (int*)ws;             ws += MAXNB * 4;
    int*   pbase        = (int*)ws;             ws += MAXNB * 4;
    float* dinv         = (float*)ws;           ws += Np * 4;
    int*   node_off     = (int*)ws;             ws += Np * 4;
    int*   node_nq      = (int*)ws;             ws += Np * 4;
    int*   bedges       = (int*)ws;             ws += ((size_t)E + 4 * MAXNB) * 4;
    int*   bedges2      = (int*)ws;             ws += ((size_t)E + 4 * Np) * 4;
    unsigned short* h1b = (unsigned short*)ws;  ws += (Np + 4) * F_HID * 2;
    // bedges region (12.82 MB) dead after k_sort:
    //   reused first as fp32 GEMM1 partials (2*n*16*4 = 12.80 MB, dead after k_fin1),
    //   then as agg1 (n*16*4 = 6.4 MB, written by k_agg1 after k_fin1).
    float* part         = (float*)bedges;
    float* agg1         = (float*)bedges;
    unsigned short* h2b = h1b;                  // h1b dead after k_agg1

    k_zero   <<<4, 256, 0, stream>>>(bucket_cnt, NB);
    k_bhist  <<<PBLK, 256, 0, stream>>>(dst, bucket_cnt, E, NB);
    k_bscan1 <<<1, 1024, 0, stream>>>(bucket_cnt, bucket_base, cursor, bedges, NB);
    k_place  <<<PBLK, 256, 0, stream>>>(src, dst, cursor, bedges, E, NB);
    k_pcount <<<NB, 256, 0, stream>>>(bucket_base, bucket_cnt, bedges, dinv, node_off, bucket_psize, n);
    k_bscan2 <<<1, 1024, 0, stream>>>(bucket_psize, pbase, NB);
    k_sort   <<<NB, 256, 0, stream>>>(bucket_base, bucket_cnt, pbase, bedges, bedges2, node_off, node_nq, n);
    k_gemm1p <<<((n + RPB - 1) / RPB) * 2, 256, 0, stream>>>(x, W1, part, n);
    k_fin1   <<<((n + 1) * 16 + 255) / 256, 256, 0, stream>>>(part, dinv, h1b, n);
    k_agg1   <<<((size_t)n * 16 + 1023) / 1024, 1024, 0, stream>>>(node_off, node_nq, bedges2, h1b, dinv, agg1, n);
    k_layer2 <<<(n + 1 + 255) / 256, 256, 0, stream>>>(agg1, b1, W2, dinv, h2b, n);
    k_agg2   <<<((size_t)n * 8 + 1023) / 1024, 1024, 0, stream>>>(node_off, node_nq, bedges2, h2b, dinv, b2, out, n);
}

// Round 2
// 523.764 us; speedup vs baseline: 1.0664x; 1.0276x over previous
//
#include <hip/hip_runtime.h>

#define F_IN 512
#define F_HID 16
#define F_OUT 7
#define BUCKET 128          // nodes per bucket
#define LB 7                // log2(BUCKET)
#define TRASH 128           // dl value for sentinel pad edges in bedges
#define PADV 128            // packed sentinel: src=0, dl=TRASH
#define CHUNK 4096          // edges per partition block (782 blocks -> ~3 blocks/CU)
#define MAXNB 1024          // max buckets supported by scans

// GEMM1 tiling
#define RPB 256             // rows per block
#define KC 32               // staged k-chunk
#define KHALF 256           // K range per split block (F_IN / KSPLIT)
#define LSTRIDE 33          // LDS row stride (pad: 2-way bank aliasing = free)

typedef int   int4v   __attribute__((ext_vector_type(4)));
typedef float float4v __attribute__((ext_vector_type(4)));
typedef unsigned int uint4v __attribute__((ext_vector_type(4)));

static __device__ __forceinline__ unsigned short f2bf(float f) {   // RNE
    unsigned int u = __float_as_uint(f);
    u += 0x7FFFu + ((u >> 16) & 1u);
    return (unsigned short)(u >> 16);
}
static __device__ __forceinline__ float bf2f(unsigned short s) {
    return __uint_as_float((unsigned int)s << 16);
}

// ---------------- hist: per-block LDS histogram -> coalesced global row ----------------
// No global atomics. bh[blk*NBA + i] = count of bucket i in this block's chunk.
__global__ __launch_bounds__(256) void k_hist(const int* __restrict__ dst,
                                              int* __restrict__ bh, int E, int NB, int NBA) {
    __shared__ int hist[MAXNB];
    int t = threadIdx.x, blk = blockIdx.x;
    for (int i = t; i < NB; i += 256) hist[i] = 0;
    __syncthreads();
    int base = blk * CHUNK;
#pragma unroll
    for (int it = 0; it < CHUNK / 1024; ++it) {
        int e = base + (it * 256 + t) * 4;
        if (e < E) {                                   // E % 4 == 0 -> whole quad valid
            int4v d4 = __builtin_nontemporal_load((const int4v*)(dst + e));
            atomicAdd(&hist[d4.x >> LB], 1);
            atomicAdd(&hist[d4.y >> LB], 1);
            atomicAdd(&hist[d4.z >> LB], 1);
            atomicAdd(&hist[d4.w >> LB], 1);
        }
    }
    __syncthreads();
    int* row = bh + (size_t)blk * NBA;
    for (int i = t; i < NB; i += 256) row[i] = hist[i];
}

// ---------------- column scan: bh column i -> exclusive prefix over blocks ----------------
// One wave per bucket. Also emits true bucket counts.
__global__ __launch_bounds__(64) void k_cscan(int* __restrict__ bh, int* __restrict__ bucket_cnt,
                                              int PBLK, int NBA) {
    int i = blockIdx.x;            // bucket
    int lane = threadIdx.x;        // 0..63
    int carry = 0;
    for (int k0 = 0; k0 < PBLK; k0 += 64) {
        int b = k0 + lane;
        int v = (b < PBLK) ? bh[(size_t)b * NBA + i] : 0;
        int s = v;
#pragma unroll
        for (int off = 1; off < 64; off <<= 1) {
            int u = __shfl_up(s, off);
            if (lane >= off) s += u;
        }
        if (b < PBLK) bh[(size_t)b * NBA + i] = carry + s - v;   // exclusive prefix
        carry += __shfl(s, 63);
    }
    if (lane == 0) bucket_cnt[i] = carry;
}

// ---- scan 1: exclusive scan of 4-aligned bucket counts + sentinel pad tails ----
__global__ void k_bscan1(const int* __restrict__ bucket_cnt, int* __restrict__ bucket_base,
                         int* __restrict__ bedges, int NB) {
    __shared__ int sm[MAXNB];
    int t = threadIdx.x;                       // 1024 threads
    int c = (t < NB) ? bucket_cnt[t] : 0;
    int ca = (c + 3) & ~3;
    sm[t] = ca;
    __syncthreads();
    for (int off = 1; off < MAXNB; off <<= 1) {
        int v = sm[t];
        int add = (t >= off) ? sm[t - off] : 0;
        __syncthreads();
        sm[t] = v + add;
        __syncthreads();
    }
    if (t < NB) {
        int base = sm[t] - ca;
        bucket_base[t] = base;
        for (int i = c; i < ca; ++i) bedges[base + i] = PADV;
    }
}

// ---------------- place: single pass, LDS cursors preloaded from scanned bases ----------------
__global__ __launch_bounds__(256) void k_place2(
        const int* __restrict__ src, const int* __restrict__ dst,
        const int* __restrict__ bucket_base, const int* __restrict__ bh,
        int* __restrict__ bedges, int E, int NB, int NBA) {
    __shared__ int lcur[MAXNB];
    int t = threadIdx.x, blk = blockIdx.x;
    const int* row = bh + (size_t)blk * NBA;
    for (int i = t; i < NB; i += 256) lcur[i] = bucket_base[i] + row[i];
    __syncthreads();
    int base = blk * CHUNK;
#pragma unroll
    for (int it = 0; it < CHUNK / 1024; ++it) {
        int e = base + (it * 256 + t) * 4;
        if (e < E) {
            int4v d4 = __builtin_nontemporal_load((const int4v*)(dst + e));
            int4v s4 = __builtin_nontemporal_load((const int4v*)(src + e));
            int p0 = atomicAdd(&lcur[d4.x >> LB], 1);
            int p1 = atomicAdd(&lcur[d4.y >> LB], 1);
            int p2 = atomicAdd(&lcur[d4.z >> LB], 1);
            int p3 = atomicAdd(&lcur[d4.w >> LB], 1);
            __builtin_nontemporal_store((s4.x << 8) | (d4.x & (BUCKET - 1)), bedges + p0);
            __builtin_nontemporal_store((s4.y << 8) | (d4.y & (BUCKET - 1)), bedges + p1);
            __builtin_nontemporal_store((s4.z << 8) | (d4.z & (BUCKET - 1)), bedges + p2);
            __builtin_nontemporal_store((s4.w << 8) | (d4.w & (BUCKET - 1)), bedges + p3);
        }
    }
}

// ---- per-bucket: degree hist -> dinv, within-bucket 4-padded offsets, bucket padded size ----
__global__ void k_pcount(const int* __restrict__ bucket_base, const int* __restrict__ bucket_cnt,
                         const int* __restrict__ bedges, float* __restrict__ dinv,
                         int* __restrict__ node_off, int* __restrict__ bucket_psize, int n) {
    __shared__ int cnt[TRASH + 8];             // bins 0..128 (128 = sentinel trash)
    __shared__ int sc[BUCKET];
    int b = blockIdx.x, t = threadIdx.x;       // 256 threads
    for (int i = t; i < TRASH + 8; i += 256) cnt[i] = 0;
    __syncthreads();
    int base = bucket_base[b], ne = bucket_cnt[b];
    int nqq = (ne + 3) >> 2;
    for (int qi = t; qi < nqq; qi += 256) {
        int4v q = __builtin_nontemporal_load((const int4v*)(bedges + base + (qi << 2)));
        atomicAdd(&cnt[q.x & 255], 1);
        atomicAdd(&cnt[q.y & 255], 1);
        atomicAdd(&cnt[q.z & 255], 1);
        atomicAdd(&cnt[q.w & 255], 1);
    }
    __syncthreads();
    int p = 0;
    if (t < BUCKET) { p = (cnt[t] + 3) & ~3; sc[t] = p; }
    __syncthreads();
    for (int off = 1; off < BUCKET; off <<= 1) {
        int v = 0;
        if (t < BUCKET) { v = sc[t]; if (t >= off) v += sc[t - off]; }
        __syncthreads();
        if (t < BUCKET) sc[t] = v;
        __syncthreads();
    }
    if (t < BUCKET) {
        int node = b * BUCKET + t;
        if (node < n) {
            dinv[node] = rsqrtf((float)(cnt[t] + 1));   // +1 self-loop
            node_off[node] = sc[t] - p;                 // within-bucket padded offset (woff)
        }
        if (t == BUCKET - 1) bucket_psize[b] = sc[t];
    }
}

// ---- scan 2: exclusive scan of padded bucket sizes -> pbase ----
__global__ void k_bscan2(const int* __restrict__ bucket_psize, int* __restrict__ pbase, int NB) {
    __shared__ int sm[MAXNB];
    int t = threadIdx.x;                       // 1024 threads
    int c = (t < NB) ? bucket_psize[t] : 0;
    sm[t] = c;
    __syncthreads();
    for (int off = 1; off < MAXNB; off <<= 1) {
        int v = sm[t];
        int add = (t >= off) ? sm[t - off] : 0;
        __syncthreads();
        sm[t] = v + add;
        __syncthreads();
    }
    if (t < NB) pbase[t] = sm[t] - c;
}

// ---- per-bucket counting sort by dl: bedges -> bedges2 (src only, per-node 4-padded runs) ----
__global__ void k_sort(const int* __restrict__ bucket_base, const int* __restrict__ bucket_cnt,
                       const int* __restrict__ pbase, const int* __restrict__ bedges,
                       int* __restrict__ bedges2, int* __restrict__ node_off,
                       int* __restrict__ node_nq, int n) {
    __shared__ int cur[BUCKET];
    __shared__ int woffs[BUCKET];
    int b = blockIdx.x, t = threadIdx.x;       // 256 threads
    int pb = pbase[b];
    if (t < BUCKET) {
        int node = b * BUCKET + t;
        int w = (node < n) ? node_off[node] : 0;
        woffs[t] = w;
        cur[t] = w;
    }
    __syncthreads();
    int base = bucket_base[b], ne = bucket_cnt[b];
    int nqq = (ne + 3) >> 2;
    for (int qi = t; qi < nqq; qi += 256) {
        int4v q = __builtin_nontemporal_load((const int4v*)(bedges + base + (qi << 2)));
        int v, dl, pos;
        v = q.x; dl = v & 255;
        if (dl < BUCKET) { pos = atomicAdd(&cur[dl], 1); bedges2[pb + pos] = v >> 8; }
        v = q.y; dl = v & 255;
        if (dl < BUCKET) { pos = atomicAdd(&cur[dl], 1); bedges2[pb + pos] = v >> 8; }
        v = q.z; dl = v & 255;
        if (dl < BUCKET) { pos = atomicAdd(&cur[dl], 1); bedges2[pb + pos] = v >> 8; }
        v = q.w; dl = v & 255;
        if (dl < BUCKET) { pos = atomicAdd(&cur[dl], 1); bedges2[pb + pos] = v >> 8; }
    }
    __syncthreads();
    if (t < BUCKET) {
        int node = b * BUCKET + t;
        if (node < n) {
            int w = woffs[t];
            int endc = cur[t];
            int cnt = endc - w;
            int p = (cnt + 3) & ~3;
            for (int i = endc; i < w + p; ++i) bedges2[pb + i] = n;   // sentinel -> zero row
            node_off[node] = pb + w;                                  // now GLOBAL offset
            node_nq[node] = p >> 2;
        }
    }
}

// -------- GEMM1: K-split x2, LDS-coalesced x staging, fp32 partials --------
// block = 256 threads = 256 rows, K-half of 256. Thread-per-row compute keeps W
// wave-uniform (s_load streamed). x staged [256][32] per chunk via full-128B-line
// coalesced loads; LSTRIDE=33 pad -> 2-way bank aliasing (free).
__global__ __launch_bounds__(256) void k_gemm1p(
        const float* __restrict__ x, const float* __restrict__ W,
        float* __restrict__ part, int n) {
    __shared__ float xs[RPB * LSTRIDE];        // 33792 B
    int b  = blockIdx.x >> 1;
    int ks = blockIdx.x & 1;
    int r0 = b * RPB;
    int t  = threadIdx.x;
    int r  = r0 + t;
    int kbase = ks * KHALF;

    float acc[F_HID];
#pragma unroll
    for (int c = 0; c < F_HID; ++c) acc[c] = 0.0f;

    int lr0 = t >> 3;                           // 0..31 (stage row group)
    int c4  = t & 7;                            // 0..7  (float4 slot: 8 x 16B = 128B/row)

    for (int kc = 0; kc < KHALF; kc += KC) {
        __syncthreads();                        // xs reads of previous chunk done
#pragma unroll
        for (int j = 0; j < 8; ++j) {
            int lr = j * 32 + lr0;
            int gr = r0 + lr;
            float4v v = {0.0f, 0.0f, 0.0f, 0.0f};
            if (gr < n)
                v = *(const float4v*)(x + (size_t)gr * F_IN + kbase + kc + c4 * 4);
            float* d = xs + lr * LSTRIDE + c4 * 4;
            d[0] = v.x; d[1] = v.y; d[2] = v.z; d[3] = v.w;
        }
        __syncthreads();
        if (r < n) {
            const float* xrow = xs + t * LSTRIDE;
            const float* Wk = W + (size_t)(kbase + kc) * F_HID;
#pragma unroll
            for (int k = 0; k < KC; ++k) {
                float xv = xrow[k];
#pragma unroll
                for (int c = 0; c < F_HID; ++c)
                    acc[c] = fmaf(xv, Wk[k * F_HID + c], acc[c]);
            }
        }
    }
    if (r < n) {
        float4v* o = (float4v*)(part + ((size_t)ks * n + r) * F_HID);
        float4v w0 = {acc[0],  acc[1],  acc[2],  acc[3]};
        float4v w1 = {acc[4],  acc[5],  acc[6],  acc[7]};
        float4v w2 = {acc[8],  acc[9],  acc[10], acc[11]};
        float4v w3 = {acc[12], acc[13], acc[14], acc[15]};
        o[0] = w0; o[1] = w1; o[2] = w2; o[3] = w3;
    }
}

// -------- finalize GEMM1: sum K-split partials, scale by dinv, -> bf16 h1b --------
__global__ void k_fin1(const float* __restrict__ part, const float* __restrict__ dinv,
                       unsigned short* __restrict__ h1b, int n) {
    int tg = blockIdx.x * 256 + threadIdx.x;
    int r = tg >> 4, c = tg & 15;
    if (r > n) return;
    if (r == n) { h1b[(size_t)r * F_HID + c] = 0; return; }
    float v = part[(size_t)r * F_HID + c] + part[((size_t)n + r) * F_HID + c];
    h1b[(size_t)r * F_HID + c] = f2bf(dinv[r] * v);
}

// ------ agg layer 1: 16 lanes/node, CSR quads, REGISTER accumulation, no atomics ------
__global__ __launch_bounds__(1024) void k_agg1(
        const int* __restrict__ node_off, const int* __restrict__ node_nq,
        const int* __restrict__ bedges2, const unsigned short* __restrict__ h1b,
        const float* __restrict__ dinv, float* __restrict__ agg1, int n) {
    int tg = blockIdx.x * 1024 + threadIdx.x;
    int node = tg >> 4, c = tg & 15;
    if (node >= n) return;
    int off = node_off[node], nq = node_nq[node];
    float acc = bf2f(h1b[(size_t)node * F_HID + c]);    // self-loop (pre-scaled)
    for (int q = 0; q < nq; ++q) {
        int4v s = *(const int4v*)(bedges2 + off + (q << 2));
        float v0 = bf2f(h1b[(size_t)s.x * F_HID + c]);
        float v1 = bf2f(h1b[(size_t)s.y * F_HID + c]);
        float v2 = bf2f(h1b[(size_t)s.z * F_HID + c]);
        float v3 = bf2f(h1b[(size_t)s.w * F_HID + c]);
        acc += v0 + v1 + v2 + v3;
    }
    agg1[(size_t)node * F_HID + c] = dinv[node] * acc;
}

// ---- relu+bias1+GEMM2, h2b = bf16(dinv * h2) (stride 8, col7 = 0); row n zeros ----
__global__ void k_layer2(const float* __restrict__ agg1, const float* __restrict__ b1,
                         const float* __restrict__ W2, const float* __restrict__ dinv,
                         unsigned short* __restrict__ h2b, int n) {
    int r = blockIdx.x * blockDim.x + threadIdx.x;
    if (r > n) return;
    if (r == n) {
        uint4v z = {0u, 0u, 0u, 0u};
        *(uint4v*)(h2b + (size_t)r * 8) = z;
        return;
    }
    float z[F_HID];
    const float4* ai = (const float4*)(agg1 + (size_t)r * F_HID);
#pragma unroll
    for (int q = 0; q < 4; ++q) {
        float4 v = ai[q];
        z[q * 4 + 0] = fmaxf(v.x + b1[q * 4 + 0], 0.0f);
        z[q * 4 + 1] = fmaxf(v.y + b1[q * 4 + 1], 0.0f);
        z[q * 4 + 2] = fmaxf(v.z + b1[q * 4 + 2], 0.0f);
        z[q * 4 + 3] = fmaxf(v.w + b1[q * 4 + 3], 0.0f);
    }
    float h[F_OUT];
#pragma unroll
    for (int c = 0; c < F_OUT; ++c) h[c] = 0.0f;
#pragma unroll
    for (int k = 0; k < F_HID; ++k)
#pragma unroll
        for (int c = 0; c < F_OUT; ++c)
            h[c] = fmaf(z[k], W2[k * F_OUT + c], h[c]);
    float dv = dinv[r];
    uint4v w;
    w.x = (unsigned)f2bf(dv * h[0]) | ((unsigned)f2bf(dv * h[1]) << 16);
    w.y = (unsigned)f2bf(dv * h[2]) | ((unsigned)f2bf(dv * h[3]) << 16);
    w.z = (unsigned)f2bf(dv * h[4]) | ((unsigned)f2bf(dv * h[5]) << 16);
    w.w = (unsigned)f2bf(dv * h[6]);
    *(uint4v*)(h2b + (size_t)r * 8) = w;
}

// ------ agg layer 2: 8 lanes/node, CSR quads, register accumulation, writes out ------
__global__ __launch_bounds__(1024) void k_agg2(
        const int* __restrict__ node_off, const int* __restrict__ node_nq,
        const int* __restrict__ bedges2, const unsigned short* __restrict__ h2b,
        const float* __restrict__ dinv, const float* __restrict__ b2,
        float* __restrict__ out, int n) {
    int tg = blockIdx.x * 1024 + threadIdx.x;
    int node = tg >> 3, c = tg & 7;
    if (node >= n) return;
    int off = node_off[node], nq = node_nq[node];
    float acc = bf2f(h2b[(size_t)node * 8 + c]);        // self-loop (col7 = 0)
    for (int q = 0; q < nq; ++q) {
        int4v s = *(const int4v*)(bedges2 + off + (q << 2));
        float v0 = bf2f(h2b[(size_t)s.x * 8 + c]);
        float v1 = bf2f(h2b[(size_t)s.y * 8 + c]);
        float v2 = bf2f(h2b[(size_t)s.z * 8 + c]);
        float v3 = bf2f(h2b[(size_t)s.w * 8 + c]);
        acc += v0 + v1 + v2 + v3;
    }
    if (c < F_OUT)
        out[(size_t)node * F_OUT + c] = dinv[node] * acc + b2[c];
}

extern "C" void kernel_launch(void* const* d_in, const int* in_sizes, int n_in,
                              void* d_out, int out_size, void* d_ws, size_t ws_size,
                              hipStream_t stream) {
    const float* x  = (const float*)d_in[0];
    const int*   ei = (const int*)d_in[1];      // int64 in source but JAX x64 off -> int32
    const float* W1 = (const float*)d_in[2];
    const float* b1 = (const float*)d_in[3];
    const float* W2 = (const float*)d_in[4];
    const float* b2 = (const float*)d_in[5];
    float* out = (float*)d_out;

    const int n = in_sizes[0] / F_IN;       // 100000
    const int E = in_sizes[1] / 2;          // 3200000
    const int* src = ei;
    const int* dst = ei + E;

    const int NB = (n + BUCKET - 1) / BUCKET;   // 782 (<= MAXNB)
    const int NBA = (NB + 3) & ~3;              // 784 (16B-aligned rows)
    const int PBLK = (E + CHUNK - 1) / CHUNK;   // 782

    // workspace layout (16B-aligned sections)
    size_t Np = ((size_t)n + 3) & ~(size_t)3;
    char* ws = (char*)d_ws;
    int*   bucket_cnt   = (int*)ws;             ws += MAXNB * 4;
    int*   bucket_base  = (int*)ws;             ws += MAXNB * 4;
    int*   bucket_psize = (int*)ws;             ws += MAXNB * 4;
    int*   pbase        = (int*)ws;             ws += MAXNB * 4;
    int*   bh           = (int*)ws;             ws += (size_t)PBLK * NBA * 4;   // 2.45 MB
    float* dinv         = (float*)ws;           ws += Np * 4;
    int*   node_off     = (int*)ws;             ws += Np * 4;
    int*   node_nq      = (int*)ws;             ws += Np * 4;
    int*   bedges       = (int*)ws;             ws += ((size_t)E + 4 * MAXNB) * 4;
    int*   bedges2      = (int*)ws;             ws += ((size_t)E + 4 * Np) * 4;
    unsigned short* h1b = (unsigned short*)ws;  ws += (Np + 4) * F_HID * 2;
    // bedges region (12.82 MB) dead after k_sort:
    //   reused first as fp32 GEMM1 partials (2*n*16*4 = 12.80 MB, dead after k_fin1),
    //   then as agg1 (n*16*4 = 6.4 MB, written by k_agg1 after k_fin1).
    float* part         = (float*)bedges;
    float* agg1         = (float*)bedges;
    unsigned short* h2b = h1b;                  // h1b dead after k_agg1

    k_hist   <<<PBLK, 256, 0, stream>>>(dst, bh, E, NB, NBA);
    k_cscan  <<<NB, 64, 0, stream>>>(bh, bucket_cnt, PBLK, NBA);
    k_bscan1 <<<1, 1024, 0, stream>>>(bucket_cnt, bucket_base, bedges, NB);
    k_place2 <<<PBLK, 256, 0, stream>>>(src, dst, bucket_base, bh, bedges, E, NB, NBA);
    k_pcount <<<NB, 256, 0, stream>>>(bucket_base, bucket_cnt, bedges, dinv, node_off, bucket_psize, n);
    k_bscan2 <<<1, 1024, 0, stream>>>(bucket_psize, pbase, NB);
    k_sort   <<<NB, 256, 0, stream>>>(bucket_base, bucket_cnt, pbase, bedges, bedges2, node_off, node_nq, n);
    k_gemm1p <<<((n + RPB - 1) / RPB) * 2, 256, 0, stream>>>(x, W1, part, n);
    k_fin1   <<<((n + 1) * 16 + 255) / 256, 256, 0, stream>>>(part, dinv, h1b, n);
    k_agg1   <<<((size_t)n * 16 + 1023) / 1024, 1024, 0, stream>>>(node_off, node_nq, bedges2, h1b, dinv, agg1, n);
    k_layer2 <<<(n + 1 + 255) / 256, 256, 0, stream>>>(agg1, b1, W2, dinv, h2b, n);
    k_agg2   <<<((size_t)n * 8 + 1023) / 1024, 1024, 0, stream>>>(node_off, node_nq, bedges2, h2b, dinv, b2, out, n);
}

// Round 3
// 469.953 us; speedup vs baseline: 1.1885x; 1.1145x over previous
//
#include <hip/hip_runtime.h>

#define F_IN 512
#define F_HID 16
#define F_OUT 7
#define BUCKET 128          // nodes per bucket
#define LB 7                // log2(BUCKET)
#define TRASH 128           // dl value for sentinel pad edges in bedges
#define PADV 128            // packed sentinel: src=0, dl=TRASH
#define CHUNK 4096          // edges per partition block
#define MAXNB 1024          // max buckets supported by scans

// GEMM1 tiling
#define RPB 256             // rows per block
#define KC 32               // staged k-chunk
#define KHALF 256           // K range per split block (F_IN / KSPLIT)
#define LSTRIDE 33          // LDS row stride (pad: 2-way bank aliasing = free)

typedef int   int4v   __attribute__((ext_vector_type(4)));
typedef float float4v __attribute__((ext_vector_type(4)));
typedef unsigned int uint4v __attribute__((ext_vector_type(4)));

static __device__ __forceinline__ unsigned short f2bf(float f) {   // RNE
    unsigned int u = __float_as_uint(f);
    u += 0x7FFFu + ((u >> 16) & 1u);
    return (unsigned short)(u >> 16);
}
static __device__ __forceinline__ float bf2f(unsigned short s) {
    return __uint_as_float((unsigned int)s << 16);
}

// ---------------- hist: per-block LDS histogram -> coalesced global row ----------------
// No global atomics. bh[blk*NBA + i] = count of bucket i in this block's chunk.
__global__ __launch_bounds__(256) void k_hist(const int* __restrict__ dst,
                                              int* __restrict__ bh, int E, int NB, int NBA) {
    __shared__ int hist[MAXNB];
    int t = threadIdx.x, blk = blockIdx.x;
    for (int i = t; i < NB; i += 256) hist[i] = 0;
    __syncthreads();
    int base = blk * CHUNK;
#pragma unroll
    for (int it = 0; it < CHUNK / 1024; ++it) {
        int e = base + (it * 256 + t) * 4;
        if (e < E) {                                   // E % 4 == 0 -> whole quad valid
            int4v d4 = __builtin_nontemporal_load((const int4v*)(dst + e));
            atomicAdd(&hist[d4.x >> LB], 1);
            atomicAdd(&hist[d4.y >> LB], 1);
            atomicAdd(&hist[d4.z >> LB], 1);
            atomicAdd(&hist[d4.w >> LB], 1);
        }
    }
    __syncthreads();
    int* row = bh + (size_t)blk * NBA;
    for (int i = t; i < NB; i += 256) row[i] = hist[i];
}

// ---------------- column scan: bh column i -> exclusive prefix over blocks ----------------
// One wave per bucket. Also emits true bucket counts.
__global__ __launch_bounds__(64) void k_cscan(int* __restrict__ bh, int* __restrict__ bucket_cnt,
                                              int PBLK, int NBA) {
    int i = blockIdx.x;            // bucket
    int lane = threadIdx.x;        // 0..63
    int carry = 0;
    for (int k0 = 0; k0 < PBLK; k0 += 64) {
        int b = k0 + lane;
        int v = (b < PBLK) ? bh[(size_t)b * NBA + i] : 0;
        int s = v;
#pragma unroll
        for (int off = 1; off < 64; off <<= 1) {
            int u = __shfl_up(s, off);
            if (lane >= off) s += u;
        }
        if (b < PBLK) bh[(size_t)b * NBA + i] = carry + s - v;   // exclusive prefix
        carry += __shfl(s, 63);
    }
    if (lane == 0) bucket_cnt[i] = carry;
}

// ---- scan 1: exclusive scan of 4-aligned bucket counts + sentinel pad tails ----
__global__ void k_bscan1(const int* __restrict__ bucket_cnt, int* __restrict__ bucket_base,
                         int* __restrict__ bedges, int NB) {
    __shared__ int sm[MAXNB];
    int t = threadIdx.x;                       // 1024 threads
    int c = (t < NB) ? bucket_cnt[t] : 0;
    int ca = (c + 3) & ~3;
    sm[t] = ca;
    __syncthreads();
    for (int off = 1; off < MAXNB; off <<= 1) {
        int v = sm[t];
        int add = (t >= off) ? sm[t - off] : 0;
        __syncthreads();
        sm[t] = v + add;
        __syncthreads();
    }
    if (t < NB) {
        int base = sm[t] - ca;
        bucket_base[t] = base;
        for (int i = c; i < ca; ++i) bedges[base + i] = PADV;
    }
}

// ------- place: block rank-and-reorder, then run-coalesced write-out (low write-amp) -------
// Phase 1: edges -> regs, LDS hist. Phase 2: block-local exclusive scan (1024-wide).
// Phase 3: rank via LDS cursors, reorder packed edges into LDS.
// Phase 4: write-out; consecutive lanes in a bucket run hit consecutive global addrs.
__global__ __launch_bounds__(256) void k_place3(
        const int* __restrict__ src, const int* __restrict__ dst,
        const int* __restrict__ bucket_base, const int* __restrict__ bh,
        int* __restrict__ bedges, int E, int NB, int NBA) {
    __shared__ int h[MAXNB];                   // hist -> exclusive cursor
    __shared__ int s[MAXNB];                   // inclusive scan -> dbase
    __shared__ int sedge[CHUNK];               // 16 KB reordered packed edges
    __shared__ unsigned short sbkt[CHUNK];     // 8 KB bucket id per slot
    int t = threadIdx.x, blk = blockIdx.x;
    for (int i = t; i < MAXNB; i += 256) h[i] = 0;
    __syncthreads();
    int base = blk * CHUNK;
    int4v d4[4], s4[4];
#pragma unroll
    for (int it = 0; it < 4; ++it) {
        int e = base + (it * 256 + t) * 4;
        if (e < E) {                           // E % 4 == 0 -> whole quad valid
            d4[it] = __builtin_nontemporal_load((const int4v*)(dst + e));
            s4[it] = __builtin_nontemporal_load((const int4v*)(src + e));
        } else {
            int sent = NB << LB;               // sentinel bucket NB (skipped at write-out)
            d4[it].x = sent; d4[it].y = sent; d4[it].z = sent; d4[it].w = sent;
            s4[it].x = 0;    s4[it].y = 0;    s4[it].z = 0;    s4[it].w = 0;
        }
        atomicAdd(&h[d4[it].x >> LB], 1);
        atomicAdd(&h[d4[it].y >> LB], 1);
        atomicAdd(&h[d4[it].z >> LB], 1);
        atomicAdd(&h[d4[it].w >> LB], 1);
    }
    __syncthreads();
    for (int i = t; i < MAXNB; i += 256) s[i] = h[i];
    __syncthreads();
    // inclusive Hillis-Steele scan of s[0..1023], 256 threads x 4
    for (int off = 1; off < MAXNB; off <<= 1) {
        int v[4];
#pragma unroll
        for (int j = 0; j < 4; ++j) {
            int i = t + j * 256;
            v[j] = s[i] + ((i >= off) ? s[i - off] : 0);
        }
        __syncthreads();
#pragma unroll
        for (int j = 0; j < 4; ++j) s[t + j * 256] = v[j];
        __syncthreads();
    }
    // h := exclusive prefix (rank cursor); s := dbase = global_start - local_excl
    const int* row = bh + (size_t)blk * NBA;
    for (int i = t; i < MAXNB; i += 256) {
        int excl = s[i] - h[i];
        h[i] = excl;
        s[i] = (i < NB) ? (bucket_base[i] + row[i] - excl) : 0;
    }
    __syncthreads();
    // rank & reorder into LDS
#pragma unroll
    for (int it = 0; it < 4; ++it) {
        int d, sv, b, p;
        d = d4[it].x; sv = s4[it].x; b = d >> LB; p = atomicAdd(&h[b], 1);
        sedge[p] = (sv << 8) | (d & (BUCKET - 1)); sbkt[p] = (unsigned short)b;
        d = d4[it].y; sv = s4[it].y; b = d >> LB; p = atomicAdd(&h[b], 1);
        sedge[p] = (sv << 8) | (d & (BUCKET - 1)); sbkt[p] = (unsigned short)b;
        d = d4[it].z; sv = s4[it].z; b = d >> LB; p = atomicAdd(&h[b], 1);
        sedge[p] = (sv << 8) | (d & (BUCKET - 1)); sbkt[p] = (unsigned short)b;
        d = d4[it].w; sv = s4[it].w; b = d >> LB; p = atomicAdd(&h[b], 1);
        sedge[p] = (sv << 8) | (d & (BUCKET - 1)); sbkt[p] = (unsigned short)b;
    }
    __syncthreads();
    // write-out: consecutive j in a bucket run -> consecutive dest (coalesced bursts)
    for (int j = t; j < CHUNK; j += 256) {
        int b = sbkt[j];
        if (b < NB)
            __builtin_nontemporal_store(sedge[j], bedges + s[b] + j);
    }
}

// ---- per-bucket: degree hist -> dinv, within-bucket 4-padded offsets, bucket padded size ----
__global__ void k_pcount(const int* __restrict__ bucket_base, const int* __restrict__ bucket_cnt,
                         const int* __restrict__ bedges, float* __restrict__ dinv,
                         int* __restrict__ node_off, int* __restrict__ bucket_psize, int n) {
    __shared__ int cnt[TRASH + 8];             // bins 0..128 (128 = sentinel trash)
    __shared__ int sc[BUCKET];
    int b = blockIdx.x, t = threadIdx.x;       // 256 threads
    for (int i = t; i < TRASH + 8; i += 256) cnt[i] = 0;
    __syncthreads();
    int base = bucket_base[b], ne = bucket_cnt[b];
    int nqq = (ne + 3) >> 2;
    for (int qi = t; qi < nqq; qi += 256) {
        int4v q = __builtin_nontemporal_load((const int4v*)(bedges + base + (qi << 2)));
        atomicAdd(&cnt[q.x & 255], 1);
        atomicAdd(&cnt[q.y & 255], 1);
        atomicAdd(&cnt[q.z & 255], 1);
        atomicAdd(&cnt[q.w & 255], 1);
    }
    __syncthreads();
    int p = 0;
    if (t < BUCKET) { p = (cnt[t] + 3) & ~3; sc[t] = p; }
    __syncthreads();
    for (int off = 1; off < BUCKET; off <<= 1) {
        int v = 0;
        if (t < BUCKET) { v = sc[t]; if (t >= off) v += sc[t - off]; }
        __syncthreads();
        if (t < BUCKET) sc[t] = v;
        __syncthreads();
    }
    if (t < BUCKET) {
        int node = b * BUCKET + t;
        if (node < n) {
            dinv[node] = rsqrtf((float)(cnt[t] + 1));   // +1 self-loop
            node_off[node] = sc[t] - p;                 // within-bucket padded offset (woff)
        }
        if (t == BUCKET - 1) bucket_psize[b] = sc[t];
    }
}

// ---- scan 2: exclusive scan of padded bucket sizes -> pbase ----
__global__ void k_bscan2(const int* __restrict__ bucket_psize, int* __restrict__ pbase, int NB) {
    __shared__ int sm[MAXNB];
    int t = threadIdx.x;                       // 1024 threads
    int c = (t < NB) ? bucket_psize[t] : 0;
    sm[t] = c;
    __syncthreads();
    for (int off = 1; off < MAXNB; off <<= 1) {
        int v = sm[t];
        int add = (t >= off) ? sm[t - off] : 0;
        __syncthreads();
        sm[t] = v + add;
        __syncthreads();
    }
    if (t < NB) pbase[t] = sm[t] - c;
}

// ---- per-bucket counting sort by dl: bedges -> bedges2 (src only, per-node 4-padded runs) ----
__global__ void k_sort(const int* __restrict__ bucket_base, const int* __restrict__ bucket_cnt,
                       const int* __restrict__ pbase, const int* __restrict__ bedges,
                       int* __restrict__ bedges2, int* __restrict__ node_off,
                       int* __restrict__ node_nq, int n) {
    __shared__ int cur[BUCKET];
    __shared__ int woffs[BUCKET];
    int b = blockIdx.x, t = threadIdx.x;       // 256 threads
    int pb = pbase[b];
    if (t < BUCKET) {
        int node = b * BUCKET + t;
        int w = (node < n) ? node_off[node] : 0;
        woffs[t] = w;
        cur[t] = w;
    }
    __syncthreads();
    int base = bucket_base[b], ne = bucket_cnt[b];
    int nqq = (ne + 3) >> 2;
    for (int qi = t; qi < nqq; qi += 256) {
        int4v q = __builtin_nontemporal_load((const int4v*)(bedges + base + (qi << 2)));
        int v, dl, pos;
        v = q.x; dl = v & 255;
        if (dl < BUCKET) { pos = atomicAdd(&cur[dl], 1); bedges2[pb + pos] = v >> 8; }
        v = q.y; dl = v & 255;
        if (dl < BUCKET) { pos = atomicAdd(&cur[dl], 1); bedges2[pb + pos] = v >> 8; }
        v = q.z; dl = v & 255;
        if (dl < BUCKET) { pos = atomicAdd(&cur[dl], 1); bedges2[pb + pos] = v >> 8; }
        v = q.w; dl = v & 255;
        if (dl < BUCKET) { pos = atomicAdd(&cur[dl], 1); bedges2[pb + pos] = v >> 8; }
    }
    __syncthreads();
    if (t < BUCKET) {
        int node = b * BUCKET + t;
        if (node < n) {
            int w = woffs[t];
            int endc = cur[t];
            int cnt = endc - w;
            int p = (cnt + 3) & ~3;
            for (int i = endc; i < w + p; ++i) bedges2[pb + i] = n;   // sentinel -> zero row
            node_off[node] = pb + w;                                  // now GLOBAL offset
            node_nq[node] = p >> 2;
        }
    }
}

// -------- GEMM1: K-split x2, LDS-coalesced x staging, fp32 partials --------
__global__ __launch_bounds__(256) void k_gemm1p(
        const float* __restrict__ x, const float* __restrict__ W,
        float* __restrict__ part, int n) {
    __shared__ float xs[RPB * LSTRIDE];        // 33792 B
    int b  = blockIdx.x >> 1;
    int ks = blockIdx.x & 1;
    int r0 = b * RPB;
    int t  = threadIdx.x;
    int r  = r0 + t;
    int kbase = ks * KHALF;

    float acc[F_HID];
#pragma unroll
    for (int c = 0; c < F_HID; ++c) acc[c] = 0.0f;

    int lr0 = t >> 3;                           // 0..31 (stage row group)
    int c4  = t & 7;                            // 0..7  (float4 slot: 8 x 16B = 128B/row)

    for (int kc = 0; kc < KHALF; kc += KC) {
        __syncthreads();                        // xs reads of previous chunk done
#pragma unroll
        for (int j = 0; j < 8; ++j) {
            int lr = j * 32 + lr0;
            int gr = r0 + lr;
            float4v v = {0.0f, 0.0f, 0.0f, 0.0f};
            if (gr < n)
                v = *(const float4v*)(x + (size_t)gr * F_IN + kbase + kc + c4 * 4);
            float* d = xs + lr * LSTRIDE + c4 * 4;
            d[0] = v.x; d[1] = v.y; d[2] = v.z; d[3] = v.w;
        }
        __syncthreads();
        if (r < n) {
            const float* xrow = xs + t * LSTRIDE;
            const float* Wk = W + (size_t)(kbase + kc) * F_HID;
#pragma unroll
            for (int k = 0; k < KC; ++k) {
                float xv = xrow[k];
#pragma unroll
                for (int c = 0; c < F_HID; ++c)
                    acc[c] = fmaf(xv, Wk[k * F_HID + c], acc[c]);
            }
        }
    }
    if (r < n) {
        float4v* o = (float4v*)(part + ((size_t)ks * n + r) * F_HID);
        float4v w0 = {acc[0],  acc[1],  acc[2],  acc[3]};
        float4v w1 = {acc[4],  acc[5],  acc[6],  acc[7]};
        float4v w2 = {acc[8],  acc[9],  acc[10], acc[11]};
        float4v w3 = {acc[12], acc[13], acc[14], acc[15]};
        o[0] = w0; o[1] = w1; o[2] = w2; o[3] = w3;
    }
}

// -------- finalize GEMM1: sum K-split partials, scale by dinv, -> bf16 h1b --------
__global__ void k_fin1(const float* __restrict__ part, const float* __restrict__ dinv,
                       unsigned short* __restrict__ h1b, int n) {
    int tg = blockIdx.x * 256 + threadIdx.x;
    int r = tg >> 4, c = tg & 15;
    if (r > n) return;
    if (r == n) { h1b[(size_t)r * F_HID + c] = 0; return; }
    float v = part[(size_t)r * F_HID + c] + part[((size_t)n + r) * F_HID + c];
    h1b[(size_t)r * F_HID + c] = f2bf(dinv[r] * v);
}

// ------ agg layer 1: 16 lanes/node, CSR quads, REGISTER accumulation, no atomics ------
__global__ __launch_bounds__(1024) void k_agg1(
        const int* __restrict__ node_off, const int* __restrict__ node_nq,
        const int* __restrict__ bedges2, const unsigned short* __restrict__ h1b,
        const float* __restrict__ dinv, float* __restrict__ agg1, int n) {
    int tg = blockIdx.x * 1024 + threadIdx.x;
    int node = tg >> 4, c = tg & 15;
    if (node >= n) return;
    int off = node_off[node], nq = node_nq[node];
    float acc = bf2f(h1b[(size_t)node * F_HID + c]);    // self-loop (pre-scaled)
    for (int q = 0; q < nq; ++q) {
        int4v s = *(const int4v*)(bedges2 + off + (q << 2));
        float v0 = bf2f(h1b[(size_t)s.x * F_HID + c]);
        float v1 = bf2f(h1b[(size_t)s.y * F_HID + c]);
        float v2 = bf2f(h1b[(size_t)s.z * F_HID + c]);
        float v3 = bf2f(h1b[(size_t)s.w * F_HID + c]);
        acc += v0 + v1 + v2 + v3;
    }
    agg1[(size_t)node * F_HID + c] = dinv[node] * acc;
}

// ---- relu+bias1+GEMM2, h2b = bf16(dinv * h2) (stride 8, col7 = 0); row n zeros ----
__global__ void k_layer2(const float* __restrict__ agg1, const float* __restrict__ b1,
                         const float* __restrict__ W2, const float* __restrict__ dinv,
                         unsigned short* __restrict__ h2b, int n) {
    int r = blockIdx.x * blockDim.x + threadIdx.x;
    if (r > n) return;
    if (r == n) {
        uint4v z = {0u, 0u, 0u, 0u};
        *(uint4v*)(h2b + (size_t)r * 8) = z;
        return;
    }
    float z[F_HID];
    const float4* ai = (const float4*)(agg1 + (size_t)r * F_HID);
#pragma unroll
    for (int q = 0; q < 4; ++q) {
        float4 v = ai[q];
        z[q * 4 + 0] = fmaxf(v.x + b1[q * 4 + 0], 0.0f);
        z[q * 4 + 1] = fmaxf(v.y + b1[q * 4 + 1], 0.0f);
        z[q * 4 + 2] = fmaxf(v.z + b1[q * 4 + 2], 0.0f);
        z[q * 4 + 3] = fmaxf(v.w + b1[q * 4 + 3], 0.0f);
    }
    float h[F_OUT];
#pragma unroll
    for (int c = 0; c < F_OUT; ++c) h[c] = 0.0f;
#pragma unroll
    for (int k = 0; k < F_HID; ++k)
#pragma unroll
        for (int c = 0; c < F_OUT; ++c)
            h[c] = fmaf(z[k], W2[k * F_OUT + c], h[c]);
    float dv = dinv[r];
    uint4v w;
    w.x = (unsigned)f2bf(dv * h[0]) | ((unsigned)f2bf(dv * h[1]) << 16);
    w.y = (unsigned)f2bf(dv * h[2]) | ((unsigned)f2bf(dv * h[3]) << 16);
    w.z = (unsigned)f2bf(dv * h[4]) | ((unsigned)f2bf(dv * h[5]) << 16);
    w.w = (unsigned)f2bf(dv * h[6]);
    *(uint4v*)(h2b + (size_t)r * 8) = w;
}

// ------ agg layer 2: 8 lanes/node, CSR quads, register accumulation, writes out ------
__global__ __launch_bounds__(1024) void k_agg2(
        const int* __restrict__ node_off, const int* __restrict__ node_nq,
        const int* __restrict__ bedges2, const unsigned short* __restrict__ h2b,
        const float* __restrict__ dinv, const float* __restrict__ b2,
        float* __restrict__ out, int n) {
    int tg = blockIdx.x * 1024 + threadIdx.x;
    int node = tg >> 3, c = tg & 7;
    if (node >= n) return;
    int off = node_off[node], nq = node_nq[node];
    float acc = bf2f(h2b[(size_t)node * 8 + c]);        // self-loop (col7 = 0)
    for (int q = 0; q < nq; ++q) {
        int4v s = *(const int4v*)(bedges2 + off + (q << 2));
        float v0 = bf2f(h2b[(size_t)s.x * 8 + c]);
        float v1 = bf2f(h2b[(size_t)s.y * 8 + c]);
        float v2 = bf2f(h2b[(size_t)s.z * 8 + c]);
        float v3 = bf2f(h2b[(size_t)s.w * 8 + c]);
        acc += v0 + v1 + v2 + v3;
    }
    if (c < F_OUT)
        out[(size_t)node * F_OUT + c] = dinv[node] * acc + b2[c];
}

extern "C" void kernel_launch(void* const* d_in, const int* in_sizes, int n_in,
                              void* d_out, int out_size, void* d_ws, size_t ws_size,
                              hipStream_t stream) {
    const float* x  = (const float*)d_in[0];
    const int*   ei = (const int*)d_in[1];      // int64 in source but JAX x64 off -> int32
    const float* W1 = (const float*)d_in[2];
    const float* b1 = (const float*)d_in[3];
    const float* W2 = (const float*)d_in[4];
    const float* b2 = (const float*)d_in[5];
    float* out = (float*)d_out;

    const int n = in_sizes[0] / F_IN;       // 100000
    const int E = in_sizes[1] / 2;          // 3200000
    const int* src = ei;
    const int* dst = ei + E;

    const int NB = (n + BUCKET - 1) / BUCKET;   // 782 (<= MAXNB-1: sentinel bucket NB fits)
    const int NBA = (NB + 3) & ~3;              // 784 (16B-aligned rows)
    const int PBLK = (E + CHUNK - 1) / CHUNK;   // 782

    // workspace layout (16B-aligned sections)
    size_t Np = ((size_t)n + 3) & ~(size_t)3;
    char* ws = (char*)d_ws;
    int*   bucket_cnt   = (int*)ws;             ws += MAXNB * 4;
    int*   bucket_base  = (int*)ws;             ws += MAXNB * 4;
    int*   bucket_psize = (int*)ws;             ws += MAXNB * 4;
    int*   pbase        = (int*)ws;             ws += MAXNB * 4;
    int*   bh           = (int*)ws;             ws += (size_t)PBLK * NBA * 4;   // 2.45 MB
    float* dinv         = (float*)ws;           ws += Np * 4;
    int*   node_off     = (int*)ws;             ws += Np * 4;
    int*   node_nq      = (int*)ws;             ws += Np * 4;
    int*   bedges       = (int*)ws;             ws += ((size_t)E + 4 * MAXNB) * 4;
    int*   bedges2      = (int*)ws;             ws += ((size_t)E + 4 * Np) * 4;
    unsigned short* h1b = (unsigned short*)ws;  ws += (Np + 4) * F_HID * 2;
    // bedges region (12.82 MB) dead after k_sort:
    //   reused first as fp32 GEMM1 partials (2*n*16*4 = 12.80 MB, dead after k_fin1),
    //   then as agg1 (n*16*4 = 6.4 MB, written by k_agg1 after k_fin1).
    float* part         = (float*)bedges;
    float* agg1         = (float*)bedges;
    unsigned short* h2b = h1b;                  // h1b dead after k_agg1

    k_hist   <<<PBLK, 256, 0, stream>>>(dst, bh, E, NB, NBA);
    k_cscan  <<<NB, 64, 0, stream>>>(bh, bucket_cnt, PBLK, NBA);
    k_bscan1 <<<1, 1024, 0, stream>>>(bucket_cnt, bucket_base, bedges, NB);
    k_place3 <<<PBLK, 256, 0, stream>>>(src, dst, bucket_base, bh, bedges, E, NB, NBA);
    k_pcount <<<NB, 256, 0, stream>>>(bucket_base, bucket_cnt, bedges, dinv, node_off, bucket_psize, n);
    k_bscan2 <<<1, 1024, 0, stream>>>(bucket_psize, pbase, NB);
    k_sort   <<<NB, 256, 0, stream>>>(bucket_base, bucket_cnt, pbase, bedges, bedges2, node_off, node_nq, n);
    k_gemm1p <<<((n + RPB - 1) / RPB) * 2, 256, 0, stream>>>(x, W1, part, n);
    k_fin1   <<<((n + 1) * 16 + 255) / 256, 256, 0, stream>>>(part, dinv, h1b, n);
    k_agg1   <<<((size_t)n * 16 + 1023) / 1024, 1024, 0, stream>>>(node_off, node_nq, bedges2, h1b, dinv, agg1, n);
    k_layer2 <<<(n + 1 + 255) / 256, 256, 0, stream>>>(agg1, b1, W2, dinv, h2b, n);
    k_agg2   <<<((size_t)n * 8 + 1023) / 1024, 1024, 0, stream>>>(node_off, node_nq, bedges2, h2b, dinv, b2, out, n);
}